// Round 5
// baseline (383.836 us; speedup 1.0000x reference)
//
#include <hip/hip_runtime.h>
#include <hip/hip_bf16.h>
#include <math.h>

// Problem constants (from reference)
#define N_HEADN 50000
#define N_TAILN 50000
#define NE      800000
#define F_IN    256
#define HH      4
#define HD      256   // H*D
#define FE      64
#define N_ETYPES 5
#define NEG_SLOPE 0.2f
#define NB_SCAN ((N_HEADN + 255) / 256)        // 196
#define NB_CVT  ((N_TAILN * F_IN) / (256 * 16)) // 3125
#define NB_HIST (NE / 256)                      // 3125
#define NB_PROJ ((N_TAILN + 63) / 64)           // 782 row-groups (x4 heads)

typedef __attribute__((ext_vector_type(8))) short bf16x8;
typedef __attribute__((ext_vector_type(4))) float f32x4;

// bf16 <-> fp32 (RNE), bit-level
static __device__ __forceinline__ unsigned short f2bf(float f) {
    unsigned u = __float_as_uint(f);
    return (unsigned short)((u + 0x7FFF + ((u >> 16) & 1)) >> 16);
}
static __device__ __forceinline__ float bf2f(unsigned short u) {
    return __uint_as_float((unsigned)u << 16);
}

// ---------------------------------------------------------------------------
// K_prep (fused):
//   blocks 0..NB_HIST-1                : histogram of head indices (counts
//                                        pre-zeroed by memsetAsync)
//   blocks NB_HIST..+NB_CVT-1          : Xb = bf16(X_tail) streaming cvt
//   block  NB_HIST+NB_CVT              : waT[h][k]
//   block  NB_HIST+NB_CVT+1            : he[ty][h]
//   blocks NB_HIST+NB_CVT+2 ..+257     : Wt[n][k] = bf16(W[k][n])
// ---------------------------------------------------------------------------
__global__ __launch_bounds__(256) void prep_kernel(const int* __restrict__ head,
                                                   int* __restrict__ counts,
                                                   const float* __restrict__ X,
                                                   unsigned short* __restrict__ Xb,
                                                   const float* __restrict__ W,
                                                   const float* __restrict__ a_l,
                                                   const float* __restrict__ W_e,
                                                   const float* __restrict__ a_e,
                                                   const float* __restrict__ edge_emb,
                                                   float* __restrict__ waT,
                                                   float* __restrict__ heo,
                                                   short* __restrict__ Wt) {
    const int b = blockIdx.x;
    if (b < NB_HIST) {
        int e = b * 256 + threadIdx.x;   // NE % 256 == 0
        atomicAdd(&counts[head[e]], 1);
    } else if (b < NB_HIST + NB_CVT) {
        size_t t = (size_t)(b - NB_HIST) * 256 + threadIdx.x;
        const float4* xp = (const float4*)X + t * 4;
        float4 v0 = xp[0], v1 = xp[1], v2 = xp[2], v3 = xp[3];
        bf16x8 o0, o1;
        o0[0] = (short)f2bf(v0.x); o0[1] = (short)f2bf(v0.y);
        o0[2] = (short)f2bf(v0.z); o0[3] = (short)f2bf(v0.w);
        o0[4] = (short)f2bf(v1.x); o0[5] = (short)f2bf(v1.y);
        o0[6] = (short)f2bf(v1.z); o0[7] = (short)f2bf(v1.w);
        o1[0] = (short)f2bf(v2.x); o1[1] = (short)f2bf(v2.y);
        o1[2] = (short)f2bf(v2.z); o1[3] = (short)f2bf(v2.w);
        o1[4] = (short)f2bf(v3.x); o1[5] = (short)f2bf(v3.y);
        o1[6] = (short)f2bf(v3.z); o1[7] = (short)f2bf(v3.w);
        bf16x8* op = (bf16x8*)(Xb + t * 16);
        op[0] = o0;
        op[1] = o1;
    } else if (b == NB_HIST + NB_CVT) {
        int k = threadIdx.x;   // 0..255
        #pragma unroll
        for (int h = 0; h < HH; ++h) {
            float s = 0.f;
            for (int d = 0; d < 64; ++d) s += a_l[h * 64 + d] * W[(size_t)k * HD + h * 64 + d];
            waT[h * 256 + k] = s;
        }
    } else if (b == NB_HIST + NB_CVT + 1) {
        __shared__ float wae[FE][HH];
        int t = threadIdx.x;          // 256 threads = 64 k x 4 h
        int k = t >> 2, h = t & 3;
        float s = 0.f;
        for (int f = 0; f < 64; ++f) s += a_e[h * 64 + f] * W_e[(size_t)k * (FE * HH) + h * 64 + f];
        wae[k][h] = s;
        __syncthreads();
        if (t < N_ETYPES * HH) {
            int ty = t >> 2, hh = t & 3;
            float acc = 0.f;
            for (int kk = 0; kk < FE; ++kk) acc += edge_emb[ty * FE + kk] * wae[kk][hh];
            heo[ty * HH + hh] = acc;
        }
    } else {
        int n = b - (NB_HIST + NB_CVT + 2), k = threadIdx.x;
        Wt[(size_t)n * 256 + k] = (short)f2bf(W[(size_t)k * 256 + n]);
    }
}

// ---------------------------------------------------------------------------
// K2a/b/c: parallel 3-phase exclusive scan of counts -> row_start, cursor
// ---------------------------------------------------------------------------
__global__ void blocksum_kernel(const int* __restrict__ counts, int* __restrict__ blockSums) {
    __shared__ int s[256];
    int t = threadIdx.x, j = blockIdx.x * 256 + t;
    s[t] = (j < N_HEADN) ? counts[j] : 0;
    __syncthreads();
    for (int off = 128; off > 0; off >>= 1) {
        if (t < off) s[t] += s[t + off];
        __syncthreads();
    }
    if (t == 0) blockSums[blockIdx.x] = s[0];
}

__global__ void blockscan_kernel(const int* __restrict__ blockSums, int* __restrict__ blockOff) {
    __shared__ int s[256];
    int t = threadIdx.x;
    int v = (t < NB_SCAN) ? blockSums[t] : 0;
    s[t] = v;
    __syncthreads();
    for (int off = 1; off < 256; off <<= 1) {
        int u = (t >= off) ? s[t - off] : 0;
        __syncthreads();
        s[t] += u;
        __syncthreads();
    }
    if (t < NB_SCAN) blockOff[t] = s[t] - v;
}

__global__ void rowstart_kernel(const int* __restrict__ counts, const int* __restrict__ blockOff,
                                int* __restrict__ row_start, int* __restrict__ cursor) {
    __shared__ int s[256];
    int t = threadIdx.x, j = blockIdx.x * 256 + t;
    int c = (j < N_HEADN) ? counts[j] : 0;
    s[t] = c;
    __syncthreads();
    for (int off = 1; off < 256; off <<= 1) {
        int u = (t >= off) ? s[t - off] : 0;
        __syncthreads();
        s[t] += u;
        __syncthreads();
    }
    int excl = blockOff[blockIdx.x] + s[t] - c;
    if (j < N_HEADN) {
        row_start[j] = excl;
        cursor[j]    = excl;
        if (j == N_HEADN - 1) row_start[N_HEADN] = excl + c;
    }
}

// ---------------------------------------------------------------------------
// K3a: hl = X_head @ waT^T  (thin GEMM, memory-bound). One wave per row.
// ---------------------------------------------------------------------------
__global__ __launch_bounds__(256) void head_dot_kernel(const float* __restrict__ X,
                                                       const float* __restrict__ waT,
                                                       float* __restrict__ hl) {
    const int wave = threadIdx.x >> 6;
    const int lane = threadIdx.x & 63;
    const int n = blockIdx.x * 4 + wave;   // N_HEADN % 4 == 0
    float4 x = ((const float4*)(X + (size_t)n * F_IN))[lane];
    float p[HH];
    #pragma unroll
    for (int h = 0; h < HH; ++h) {
        float4 w = ((const float4*)(waT + h * 256))[lane];
        p[h] = x.x * w.x + x.y * w.y + x.z * w.z + x.w * w.w;
    }
    #pragma unroll
    for (int off = 1; off < 64; off <<= 1) {
        #pragma unroll
        for (int h = 0; h < HH; ++h) p[h] += __shfl_xor(p[h], off);
    }
    if (lane < HH) hl[(size_t)n * HH + lane] = p[lane];
}

// ---------------------------------------------------------------------------
// K3b: h_tail = Xb(bf16) @ W via bf16 MFMA (16x16x32), fp32 accum.
// NEW decomposition for occupancy/latency: block = one head x 64 rows;
// wave = 16 cols (ct = wave id) x 64 rows (4 M-tiles).
//   acc = 4 x f32x4 = 16 VGPR (vs 64 before)
//   B-panel (16 cols x 256 k) = 8 bf16x8 = 32 VGPR, loaded ONCE in prologue
//   k-loop: 32 independent A-loads + 32 MFMAs, zero B traffic
// Grid = 782*4 = 3128 blocks, 12512 waves (4x more TLP than before).
// hr dot (over the head's 64 cols) combined across the 4 waves via 1KB LDS.
// A-frag: A[m=lane&15][k=quad*8+j]  B-frag: B[k=quad*8+j][n=lane&15]
// C/D:    col=lane&15, row=quad*4+reg  [m89-verified]
// Tail: clamp M-tile base to N-16 (duplicate identical stores, benign).
// ---------------------------------------------------------------------------
__global__ __launch_bounds__(256) void proj_mfma_kernel(const unsigned short* __restrict__ Xb,
                                                        const short* __restrict__ Wt,
                                                        const float* __restrict__ a,
                                                        unsigned short* __restrict__ h_out,
                                                        float* __restrict__ hr,
                                                        int N) {
    const int head = blockIdx.x & 3;
    const int n0   = (blockIdx.x >> 2) * 64;
    const int wv   = threadIdx.x >> 6;     // col-group (ct) 0..3
    const int lane = threadIdx.x & 63;
    const int quad = lane >> 4;
    const int l15  = lane & 15;

    __shared__ float hrbuf[4][64];

    int rbase[4];
    #pragma unroll
    for (int mt = 0; mt < 4; ++mt) {
        int r = n0 + mt * 16;
        rbase[mt] = (r + 16 <= N) ? r : (N - 16);   // clamp tail tiles
    }

    // B panel in registers: col = head*64 + wv*16 + l15, all 256 k
    const short* wbase = Wt + (size_t)(head * 64 + wv * 16 + l15) * 256 + quad * 8;
    bf16x8 breg[8];
    #pragma unroll
    for (int kk = 0; kk < 8; ++kk) breg[kk] = *(const bf16x8*)(wbase + kk * 32);

    f32x4 acc[4];
    #pragma unroll
    for (int mt = 0; mt < 4; ++mt) acc[mt] = (f32x4){0.f, 0.f, 0.f, 0.f};

    const unsigned short* xrow[4];
    #pragma unroll
    for (int mt = 0; mt < 4; ++mt)
        xrow[mt] = Xb + (size_t)(rbase[mt] + l15) * F_IN + quad * 8;

    #pragma unroll
    for (int kk = 0; kk < 8; ++kk) {
        bf16x8 af[4];
        #pragma unroll
        for (int mt = 0; mt < 4; ++mt) af[mt] = *(const bf16x8*)(xrow[mt] + kk * 32);
        #pragma unroll
        for (int mt = 0; mt < 4; ++mt)
            acc[mt] = __builtin_amdgcn_mfma_f32_16x16x32_bf16(af[mt], breg[kk], acc[mt], 0, 0, 0);
    }

    const float av = a[head * 64 + wv * 16 + l15];

    #pragma unroll
    for (int mt = 0; mt < 4; ++mt) {
        #pragma unroll
        for (int r = 0; r < 4; ++r) {
            int row = rbase[mt] + quad * 4 + r;
            h_out[(size_t)row * HD + head * 64 + wv * 16 + l15] = f2bf(acc[mt][r]);
        }
        // per-wave partial hr dot over this wave's 16 cols (reduce over l15)
        #pragma unroll
        for (int r = 0; r < 4; ++r) {
            float p = av * acc[mt][r];
            p += __shfl_xor(p, 1);
            p += __shfl_xor(p, 2);
            p += __shfl_xor(p, 4);
            p += __shfl_xor(p, 8);
            if (l15 == 0) hrbuf[wv][mt * 16 + quad * 4 + r] = p;
        }
    }
    __syncthreads();
    if (threadIdx.x < 64) {
        int row = threadIdx.x;        // local row 0..63
        int mt  = row >> 4;
        int rb  = (n0 + mt * 16 + 16 <= N) ? (n0 + mt * 16) : (N - 16);
        int g   = rb + (row & 15);
        float s = hrbuf[0][row] + hrbuf[1][row] + hrbuf[2][row] + hrbuf[3][row];
        hr[(size_t)g * HH + head] = s;
    }
}

// ---------------------------------------------------------------------------
// K4: scatter each edge into its CSR slot; compute ex = exp(leaky(hl+hr+he))
// for all 4 heads here (edge-parallel). packed[pos] = tail; exE[pos][h] = ex.
// ---------------------------------------------------------------------------
__global__ void scatter_kernel(const int* __restrict__ head, const int* __restrict__ tail,
                               const int* __restrict__ etype,
                               const float* __restrict__ hl, const float* __restrict__ hr,
                               const float* __restrict__ he,
                               int* __restrict__ cursor, int* __restrict__ packed,
                               float* __restrict__ exE) {
    int e = blockIdx.x * 256 + threadIdx.x;   // NE % 256 == 0
    int h0 = head[e];
    int tl = tail[e];
    int ty = etype[e];
    float4 L = *(const float4*)(hl + (size_t)h0 * HH);
    float4 R = *(const float4*)(hr + (size_t)tl * HH);
    float4 T = *(const float4*)(he + ty * HH);
    float s0 = L.x + R.x + T.x;
    float s1 = L.y + R.y + T.y;
    float s2 = L.z + R.z + T.z;
    float s3 = L.w + R.w + T.w;
    s0 = (s0 > 0.f) ? s0 : NEG_SLOPE * s0;
    s1 = (s1 > 0.f) ? s1 : NEG_SLOPE * s1;
    s2 = (s2 > 0.f) ? s2 : NEG_SLOPE * s2;
    s3 = (s3 > 0.f) ? s3 : NEG_SLOPE * s3;
    float w0 = __expf(s0), w1 = __expf(s1), w2 = __expf(s2), w3 = __expf(s3);
    int pos = atomicAdd(&cursor[h0], 1);
    packed[pos] = tl;
    *(float4*)(exE + (size_t)pos * HH) = make_float4(w0, w1, w2, w3);
}

// ---------------------------------------------------------------------------
// K5: aggregation. One wave per head node. 2 edges/iteration, 32 lanes per
// edge, each lane one DENSE uint4 (16B) of the 512B h_tail row -> every
// gather instruction covers 2 full rows with zero wasted bytes.
// lane = (g,q): g=lane>>5 edge substream, q=lane&31 owns cols 8q..8q+7
// (head h=q>>3). Index preload + shfl keeps gather addresses
// dependency-free; unroll 8 => 8 gathers in flight.
// ---------------------------------------------------------------------------
__global__ __launch_bounds__(256) void agg_kernel(const int* __restrict__ row_start,
                                                  const int* __restrict__ packed,
                                                  const float* __restrict__ exE,
                                                  const unsigned short* __restrict__ h_tail, // bf16
                                                  float* __restrict__ out) {
    const int wave = threadIdx.x >> 6;
    const int lane = threadIdx.x & 63;
    const int n = blockIdx.x * 4 + wave;      // N_HEADN % 4 == 0
    const int s = row_start[n];
    const int e = row_start[n + 1];
    const int g = lane >> 5;      // edge sub-stream 0..1
    const int q = lane & 31;      // column chunk: cols 8q..8q+7
    const int h = q >> 3;         // attention head for these cols

    float acc[8];
    #pragma unroll
    for (int c = 0; c < 8; ++c) acc[c] = 0.f;
    float z = 0.f;

    for (int base = s; base < e; base += 64) {
        const int cnt = (e - base < 64) ? (e - base) : 64;
        int myidx = 0;
        if (base + lane < e) myidx = packed[base + lane];
        #pragma unroll 8
        for (int i = 0; i < cnt; i += 2) {
            const int j = i + g;
            const int tl = __shfl(myidx, j);
            if (j < cnt) {
                const float w = exE[(size_t)(base + j) * HH + h];
                uint4 u = *(const uint4*)(h_tail + (size_t)tl * HD + q * 8);
                #pragma unroll
                for (int d = 0; d < 4; ++d) {
                    unsigned uu = ((const unsigned*)&u)[d];
                    acc[2 * d]     += w * __uint_as_float(uu << 16);
                    acc[2 * d + 1] += w * __uint_as_float(uu & 0xFFFF0000u);
                }
                z += w;
            }
        }
    }

    // combine the 2 edge sub-streams (lane ^ 32)
    #pragma unroll
    for (int c = 0; c < 8; ++c) acc[c] += __shfl_xor(acc[c], 32);
    z += __shfl_xor(z, 32);

    // lane writes cols 8q+4g .. +3 from acc[4g .. 4g+3] (dense 1KB per wave)
    float4 o;
    if (z > 0.f) {
        o.x = acc[4 * g + 0] / z;
        o.y = acc[4 * g + 1] / z;
        o.z = acc[4 * g + 2] / z;
        o.w = acc[4 * g + 3] / z;
        o.x = (o.x > 0.f) ? o.x : expm1f(o.x);
        o.y = (o.y > 0.f) ? o.y : expm1f(o.y);
        o.z = (o.z > 0.f) ? o.z : expm1f(o.z);
        o.w = (o.w > 0.f) ? o.w : expm1f(o.w);
    } else {
        o = make_float4(0.f, 0.f, 0.f, 0.f);
    }
    ((float4*)(out + (size_t)n * HD))[q * 2 + g] = o;
}

// ---------------------------------------------------------------------------
extern "C" void kernel_launch(void* const* d_in, const int* in_sizes, int n_in,
                              void* d_out, int out_size, void* d_ws, size_t ws_size,
                              hipStream_t stream) {
    const float* head_feature = (const float*)d_in[0];
    const float* tail_feature = (const float*)d_in[1];
    const int*   edge_list    = (const int*)d_in[2];   // [2, E]
    const int*   tmp_edge     = (const int*)d_in[3];   // [E]
    const float* W            = (const float*)d_in[4];
    const float* W_e          = (const float*)d_in[5];
    const float* edge_emb     = (const float*)d_in[6];
    const float* a_l          = (const float*)d_in[7];
    const float* a_r          = (const float*)d_in[8];
    const float* a_e          = (const float*)d_in[9];
    const int* head_ind = edge_list;
    const int* tail_ind = edge_list + NE;

    // Workspace carve-up (~54 MB), 16B-aligned chunks first.
    // Xb (bf16 tail features, dead after proj) ALIASES exE+packed (born in
    // scatter) — region R sized max(25.6, 16) MB.
    char* ws = (char*)d_ws;
    unsigned short* h_tail = (unsigned short*)ws; ws += sizeof(unsigned short) * (size_t)N_TAILN * HD; // 25.6 MB
    unsigned short* Xb = (unsigned short*)ws;      // 25.6 MB region R
    float* exE    = (float*)(void*)Xb;                                          // alias: 12.8 MB
    int*   packed = (int*)(void*)((char*)(void*)Xb + sizeof(float) * (size_t)NE * HH); // alias: 3.2 MB
    ws += sizeof(unsigned short) * (size_t)N_TAILN * HD;
    short* Wt        = (short*)ws; ws += sizeof(short) * 256 * 256;              // 128 KB
    float* hl        = (float*)ws; ws += sizeof(float) * (size_t)N_HEADN * HH;   // 0.8 MB
    float* hr        = (float*)ws; ws += sizeof(float) * (size_t)N_TAILN * HH;   // 0.8 MB
    float* waT       = (float*)ws; ws += sizeof(float) * HH * 256;               // 4 KB
    float* he        = (float*)ws; ws += sizeof(float) * 32;                     // padded
    int*   counts    = (int*)ws;   ws += sizeof(int) * (size_t)N_HEADN;          // 0.2 MB
    int*   row_start = (int*)ws;   ws += sizeof(int) * (size_t)(N_HEADN + 4);    // 0.2 MB
    int*   cursor    = (int*)ws;   ws += sizeof(int) * (size_t)N_HEADN;          // 0.2 MB
    int*   blockSums = (int*)ws;   ws += sizeof(int) * 256;
    int*   blockOff  = (int*)ws;   ws += sizeof(int) * 256;

    hipMemsetAsync(counts, 0, sizeof(int) * (size_t)N_HEADN, stream);

    // fused prep: hist | Xb cvt | waT | he | Wt — one dispatch
    hipLaunchKernelGGL(prep_kernel, dim3(NB_HIST + NB_CVT + 258), dim3(256), 0, stream,
                       head_ind, counts, tail_feature, Xb,
                       W, a_l, W_e, a_e, edge_emb, waT, he, Wt);

    hipLaunchKernelGGL(blocksum_kernel, dim3(NB_SCAN), dim3(256), 0, stream,
                       counts, blockSums);
    hipLaunchKernelGGL(blockscan_kernel, dim3(1), dim3(256), 0, stream,
                       blockSums, blockOff);
    hipLaunchKernelGGL(rowstart_kernel, dim3(NB_SCAN), dim3(256), 0, stream,
                       counts, blockOff, row_start, cursor);

    hipLaunchKernelGGL(head_dot_kernel, dim3(N_HEADN / 4), dim3(256), 0, stream,
                       head_feature, waT, hl);
    hipLaunchKernelGGL(proj_mfma_kernel, dim3(NB_PROJ * 4), dim3(256), 0, stream,
                       Xb, Wt, a_r, h_tail, hr, N_TAILN);

    hipLaunchKernelGGL(scatter_kernel, dim3(NE / 256), dim3(256), 0, stream,
                       head_ind, tail_ind, tmp_edge, hl, hr, he, cursor, packed, exE);

    hipLaunchKernelGGL(agg_kernel, dim3(N_HEADN / 4), dim3(256), 0, stream,
                       row_start, packed, exE, h_tail, (float*)d_out);
}

// Round 6
// 379.068 us; speedup vs baseline: 1.0126x; 1.0126x over previous
//
#include <hip/hip_runtime.h>
#include <hip/hip_bf16.h>
#include <math.h>

// Problem constants (from reference)
#define N_HEADN 50000
#define N_TAILN 50000
#define NE      800000
#define F_IN    256
#define HH      4
#define HD      256   // H*D
#define FE      64
#define N_ETYPES 5
#define NEG_SLOPE 0.2f
#define NB_SCAN ((N_HEADN + 255) / 256)        // 196
#define NB_CVT  ((N_TAILN * F_IN) / (256 * 16)) // 3125
#define NB_HIST (NE / 256)                      // 3125
#define NB_PROJ (N_TAILN / 16)                  // 3125 (exact: 16 | 50000)

typedef __attribute__((ext_vector_type(8))) short bf16x8;
typedef __attribute__((ext_vector_type(4))) float f32x4;

// bf16 <-> fp32 (RNE), bit-level
static __device__ __forceinline__ unsigned short f2bf(float f) {
    unsigned u = __float_as_uint(f);
    return (unsigned short)((u + 0x7FFF + ((u >> 16) & 1)) >> 16);
}
static __device__ __forceinline__ float bf2f(unsigned short u) {
    return __uint_as_float((unsigned)u << 16);
}

// ---------------------------------------------------------------------------
// K_prep (fused):
//   blocks 0..NB_HIST-1                : histogram of head indices (counts
//                                        pre-zeroed by memsetAsync)
//   blocks NB_HIST..+NB_CVT-1          : Xb = bf16(X_tail) streaming cvt
//   block  NB_HIST+NB_CVT              : waT[h][k]
//   block  NB_HIST+NB_CVT+1            : he[ty][h]
//   blocks NB_HIST+NB_CVT+2 ..+257     : Wt[n][k] = bf16(W[k][n])
// ---------------------------------------------------------------------------
__global__ __launch_bounds__(256) void prep_kernel(const int* __restrict__ head,
                                                   int* __restrict__ counts,
                                                   const float* __restrict__ X,
                                                   unsigned short* __restrict__ Xb,
                                                   const float* __restrict__ W,
                                                   const float* __restrict__ a_l,
                                                   const float* __restrict__ W_e,
                                                   const float* __restrict__ a_e,
                                                   const float* __restrict__ edge_emb,
                                                   float* __restrict__ waT,
                                                   float* __restrict__ heo,
                                                   short* __restrict__ Wt) {
    const int b = blockIdx.x;
    if (b < NB_HIST) {
        int e = b * 256 + threadIdx.x;   // NE % 256 == 0
        atomicAdd(&counts[head[e]], 1);
    } else if (b < NB_HIST + NB_CVT) {
        size_t t = (size_t)(b - NB_HIST) * 256 + threadIdx.x;
        const float4* xp = (const float4*)X + t * 4;
        float4 v0 = xp[0], v1 = xp[1], v2 = xp[2], v3 = xp[3];
        bf16x8 o0, o1;
        o0[0] = (short)f2bf(v0.x); o0[1] = (short)f2bf(v0.y);
        o0[2] = (short)f2bf(v0.z); o0[3] = (short)f2bf(v0.w);
        o0[4] = (short)f2bf(v1.x); o0[5] = (short)f2bf(v1.y);
        o0[6] = (short)f2bf(v1.z); o0[7] = (short)f2bf(v1.w);
        o1[0] = (short)f2bf(v2.x); o1[1] = (short)f2bf(v2.y);
        o1[2] = (short)f2bf(v2.z); o1[3] = (short)f2bf(v2.w);
        o1[4] = (short)f2bf(v3.x); o1[5] = (short)f2bf(v3.y);
        o1[6] = (short)f2bf(v3.z); o1[7] = (short)f2bf(v3.w);
        bf16x8* op = (bf16x8*)(Xb + t * 16);
        op[0] = o0;
        op[1] = o1;
    } else if (b == NB_HIST + NB_CVT) {
        int k = threadIdx.x;   // 0..255
        #pragma unroll
        for (int h = 0; h < HH; ++h) {
            float s = 0.f;
            for (int d = 0; d < 64; ++d) s += a_l[h * 64 + d] * W[(size_t)k * HD + h * 64 + d];
            waT[h * 256 + k] = s;
        }
    } else if (b == NB_HIST + NB_CVT + 1) {
        __shared__ float wae[FE][HH];
        int t = threadIdx.x;          // 256 threads = 64 k x 4 h
        int k = t >> 2, h = t & 3;
        float s = 0.f;
        for (int f = 0; f < 64; ++f) s += a_e[h * 64 + f] * W_e[(size_t)k * (FE * HH) + h * 64 + f];
        wae[k][h] = s;
        __syncthreads();
        if (t < N_ETYPES * HH) {
            int ty = t >> 2, hh = t & 3;
            float acc = 0.f;
            for (int kk = 0; kk < FE; ++kk) acc += edge_emb[ty * FE + kk] * wae[kk][hh];
            heo[ty * HH + hh] = acc;
        }
    } else {
        int n = b - (NB_HIST + NB_CVT + 2), k = threadIdx.x;
        Wt[(size_t)n * 256 + k] = (short)f2bf(W[(size_t)k * 256 + n]);
    }
}

// ---------------------------------------------------------------------------
// K2a: per-block sums of counts
// ---------------------------------------------------------------------------
__global__ void blocksum_kernel(const int* __restrict__ counts, int* __restrict__ blockSums) {
    __shared__ int s[256];
    int t = threadIdx.x, j = blockIdx.x * 256 + t;
    s[t] = (j < N_HEADN) ? counts[j] : 0;
    __syncthreads();
    for (int off = 128; off > 0; off >>= 1) {
        if (t < off) s[t] += s[t + off];
        __syncthreads();
    }
    if (t == 0) blockSums[blockIdx.x] = s[0];
}

// ---------------------------------------------------------------------------
// K2b (fused): each block redundantly scans the 196 blockSums in LDS
// (inclusive; exclusive offset = bs[bid-1]), then scans its own 256 counts
// -> row_start, cursor. Removes the former 1-block blockscan dispatch.
// ---------------------------------------------------------------------------
__global__ void rowstart_kernel(const int* __restrict__ counts,
                                const int* __restrict__ blockSums,
                                int* __restrict__ row_start, int* __restrict__ cursor) {
    __shared__ int bs[256];
    __shared__ int s[256];
    int t = threadIdx.x, j = blockIdx.x * 256 + t;
    // scan blockSums (inclusive)
    bs[t] = (t < NB_SCAN) ? blockSums[t] : 0;
    __syncthreads();
    for (int off = 1; off < 256; off <<= 1) {
        int u = (t >= off) ? bs[t - off] : 0;
        __syncthreads();
        bs[t] += u;
        __syncthreads();
    }
    const int blockOffV = (blockIdx.x == 0) ? 0 : bs[blockIdx.x - 1];
    // scan own counts (inclusive)
    int c = (j < N_HEADN) ? counts[j] : 0;
    s[t] = c;
    __syncthreads();
    for (int off = 1; off < 256; off <<= 1) {
        int u = (t >= off) ? s[t - off] : 0;
        __syncthreads();
        s[t] += u;
        __syncthreads();
    }
    int excl = blockOffV + s[t] - c;
    if (j < N_HEADN) {
        row_start[j] = excl;
        cursor[j]    = excl;
        if (j == N_HEADN - 1) row_start[N_HEADN] = excl + c;
    }
}

// ---------------------------------------------------------------------------
// K3a: hl = X_head @ waT^T  (thin GEMM, memory-bound). One wave per row.
// ---------------------------------------------------------------------------
__global__ __launch_bounds__(256) void head_dot_kernel(const float* __restrict__ X,
                                                       const float* __restrict__ waT,
                                                       float* __restrict__ hl) {
    const int wave = threadIdx.x >> 6;
    const int lane = threadIdx.x & 63;
    const int n = blockIdx.x * 4 + wave;   // N_HEADN % 4 == 0
    float4 x = ((const float4*)(X + (size_t)n * F_IN))[lane];
    float p[HH];
    #pragma unroll
    for (int h = 0; h < HH; ++h) {
        float4 w = ((const float4*)(waT + h * 256))[lane];
        p[h] = x.x * w.x + x.y * w.y + x.z * w.z + x.w * w.w;
    }
    #pragma unroll
    for (int off = 1; off < 64; off <<= 1) {
        #pragma unroll
        for (int h = 0; h < HH; ++h) p[h] += __shfl_xor(p[h], off);
    }
    if (lane < HH) hl[(size_t)n * HH + lane] = p[lane];
}

// ---------------------------------------------------------------------------
// K3b v3: h_tail = Xb(bf16) @ W via bf16 MFMA with SWAPPED operands:
//   D = Wt · Xb^T  (A-frag from Wt: m = w-col; B-frag from Xb: n = x-row)
// so each lane's 4 acc regs are 4 CONSECUTIVE w-cols of ONE x-row ->
// packed 8B stores (4x fewer store insts, no 2B scatter / write-allocate).
// Block = 16 x-rows (3125 blocks, exact), wave = one head:
//   acc = 4 f32x4 = 16 VGPR; xf panel = 8 bf16x8 = 32 VGPR loaded once;
//   32 Wt loads (128KB matrix, L2-hot) + 32 MFMA, fully unrolled.
// No Xb duplication across blocks. hr dot: quad-reduce via 2 shfls, no LDS.
// A-frag: A[m=lane&15][k=quad*8+j]  B-frag: B[k=quad*8+j][n=lane&15]
// C/D:    col(n)=lane&15, row(m)=quad*4+reg  [m89-verified]
// ---------------------------------------------------------------------------
__global__ __launch_bounds__(256) void proj_mfma_kernel(const unsigned short* __restrict__ Xb,
                                                        const short* __restrict__ Wt,
                                                        const float* __restrict__ a,
                                                        unsigned short* __restrict__ h_out,
                                                        float* __restrict__ hr) {
    const int h    = threadIdx.x >> 6;     // wave = head 0..3
    const int lane = threadIdx.x & 63;
    const int quad = lane >> 4;
    const int l15  = lane & 15;
    const int r0   = blockIdx.x * 16;      // x-row base

    // B-frags from Xb: lane l15 = x-row r0+l15, k-chunk = quad*8 + kk*32
    const unsigned short* xbase = Xb + (size_t)(r0 + l15) * F_IN + quad * 8;
    bf16x8 xf[8];
    #pragma unroll
    for (int kk = 0; kk < 8; ++kk) xf[kk] = *(const bf16x8*)(xbase + kk * 32);

    f32x4 acc[4];
    #pragma unroll
    for (int ct = 0; ct < 4; ++ct) acc[ct] = (f32x4){0.f, 0.f, 0.f, 0.f};

    // A-frags from Wt: lane l15 = w-col (h*64 + ct*16 + l15)
    const short* wbase = Wt + (size_t)(h * 64 + l15) * 256 + quad * 8;

    #pragma unroll
    for (int kk = 0; kk < 8; ++kk) {
        #pragma unroll
        for (int ct = 0; ct < 4; ++ct) {
            bf16x8 wf = *(const bf16x8*)(wbase + (size_t)ct * 16 * 256 + kk * 32);
            acc[ct] = __builtin_amdgcn_mfma_f32_16x16x32_bf16(wf, xf[kk], acc[ct], 0, 0, 0);
        }
    }

    // D[m=quad*4+r -> w-col within ct-tile][n=l15 -> x-row]
    const int row = r0 + l15;
    float hp = 0.f;
    #pragma unroll
    for (int ct = 0; ct < 4; ++ct) {
        float4 av = *(const float4*)(a + h * 64 + ct * 16 + quad * 4);
        hp += av.x * acc[ct][0] + av.y * acc[ct][1]
            + av.z * acc[ct][2] + av.w * acc[ct][3];
        ushort4 pk;
        pk.x = f2bf(acc[ct][0]); pk.y = f2bf(acc[ct][1]);
        pk.z = f2bf(acc[ct][2]); pk.w = f2bf(acc[ct][3]);
        *(ushort4*)(h_out + (size_t)row * HD + h * 64 + ct * 16 + quad * 4) = pk;
    }
    // reduce across the 4 quads (same l15): full 64-col dot for this row
    hp += __shfl_xor(hp, 16);
    hp += __shfl_xor(hp, 32);
    if (lane < 16) hr[(size_t)row * HH + h] = hp;
}

// ---------------------------------------------------------------------------
// K4: scatter each edge into its CSR slot; compute ex = exp(leaky(hl+hr+he))
// for all 4 heads here (edge-parallel). packed[pos] = tail; exE[pos][h] = ex.
// ---------------------------------------------------------------------------
__global__ void scatter_kernel(const int* __restrict__ head, const int* __restrict__ tail,
                               const int* __restrict__ etype,
                               const float* __restrict__ hl, const float* __restrict__ hr,
                               const float* __restrict__ he,
                               int* __restrict__ cursor, int* __restrict__ packed,
                               float* __restrict__ exE) {
    int e = blockIdx.x * 256 + threadIdx.x;   // NE % 256 == 0
    int h0 = head[e];
    int tl = tail[e];
    int ty = etype[e];
    float4 L = *(const float4*)(hl + (size_t)h0 * HH);
    float4 R = *(const float4*)(hr + (size_t)tl * HH);
    float4 T = *(const float4*)(he + ty * HH);
    float s0 = L.x + R.x + T.x;
    float s1 = L.y + R.y + T.y;
    float s2 = L.z + R.z + T.z;
    float s3 = L.w + R.w + T.w;
    s0 = (s0 > 0.f) ? s0 : NEG_SLOPE * s0;
    s1 = (s1 > 0.f) ? s1 : NEG_SLOPE * s1;
    s2 = (s2 > 0.f) ? s2 : NEG_SLOPE * s2;
    s3 = (s3 > 0.f) ? s3 : NEG_SLOPE * s3;
    float w0 = __expf(s0), w1 = __expf(s1), w2 = __expf(s2), w3 = __expf(s3);
    int pos = atomicAdd(&cursor[h0], 1);
    packed[pos] = tl;
    *(float4*)(exE + (size_t)pos * HH) = make_float4(w0, w1, w2, w3);
}

// ---------------------------------------------------------------------------
// K5: aggregation. One wave per head node. 2 edges/iteration, 32 lanes per
// edge, each lane one DENSE uint4 (16B) of the 512B h_tail row -> every
// gather instruction covers 2 full rows with zero wasted bytes.
// lane = (g,q): g=lane>>5 edge substream, q=lane&31 owns cols 8q..8q+7
// (head h=q>>3). Index preload + shfl keeps gather addresses
// dependency-free; unroll 8 => 8 gathers in flight.
// ---------------------------------------------------------------------------
__global__ __launch_bounds__(256) void agg_kernel(const int* __restrict__ row_start,
                                                  const int* __restrict__ packed,
                                                  const float* __restrict__ exE,
                                                  const unsigned short* __restrict__ h_tail, // bf16
                                                  float* __restrict__ out) {
    const int wave = threadIdx.x >> 6;
    const int lane = threadIdx.x & 63;
    const int n = blockIdx.x * 4 + wave;      // N_HEADN % 4 == 0
    const int s = row_start[n];
    const int e = row_start[n + 1];
    const int g = lane >> 5;      // edge sub-stream 0..1
    const int q = lane & 31;      // column chunk: cols 8q..8q+7
    const int h = q >> 3;         // attention head for these cols

    float acc[8];
    #pragma unroll
    for (int c = 0; c < 8; ++c) acc[c] = 0.f;
    float z = 0.f;

    for (int base = s; base < e; base += 64) {
        const int cnt = (e - base < 64) ? (e - base) : 64;
        int myidx = 0;
        if (base + lane < e) myidx = packed[base + lane];
        #pragma unroll 8
        for (int i = 0; i < cnt; i += 2) {
            const int j = i + g;
            const int tl = __shfl(myidx, j);
            if (j < cnt) {
                const float w = exE[(size_t)(base + j) * HH + h];
                uint4 u = *(const uint4*)(h_tail + (size_t)tl * HD + q * 8);
                #pragma unroll
                for (int d = 0; d < 4; ++d) {
                    unsigned uu = ((const unsigned*)&u)[d];
                    acc[2 * d]     += w * __uint_as_float(uu << 16);
                    acc[2 * d + 1] += w * __uint_as_float(uu & 0xFFFF0000u);
                }
                z += w;
            }
        }
    }

    // combine the 2 edge sub-streams (lane ^ 32)
    #pragma unroll
    for (int c = 0; c < 8; ++c) acc[c] += __shfl_xor(acc[c], 32);
    z += __shfl_xor(z, 32);

    // lane writes cols 8q+4g .. +3 from acc[4g .. 4g+3] (dense 1KB per wave)
    float4 o;
    if (z > 0.f) {
        o.x = acc[4 * g + 0] / z;
        o.y = acc[4 * g + 1] / z;
        o.z = acc[4 * g + 2] / z;
        o.w = acc[4 * g + 3] / z;
        o.x = (o.x > 0.f) ? o.x : expm1f(o.x);
        o.y = (o.y > 0.f) ? o.y : expm1f(o.y);
        o.z = (o.z > 0.f) ? o.z : expm1f(o.z);
        o.w = (o.w > 0.f) ? o.w : expm1f(o.w);
    } else {
        o = make_float4(0.f, 0.f, 0.f, 0.f);
    }
    ((float4*)(out + (size_t)n * HD))[q * 2 + g] = o;
}

// ---------------------------------------------------------------------------
extern "C" void kernel_launch(void* const* d_in, const int* in_sizes, int n_in,
                              void* d_out, int out_size, void* d_ws, size_t ws_size,
                              hipStream_t stream) {
    const float* head_feature = (const float*)d_in[0];
    const float* tail_feature = (const float*)d_in[1];
    const int*   edge_list    = (const int*)d_in[2];   // [2, E]
    const int*   tmp_edge     = (const int*)d_in[3];   // [E]
    const float* W            = (const float*)d_in[4];
    const float* W_e          = (const float*)d_in[5];
    const float* edge_emb     = (const float*)d_in[6];
    const float* a_l          = (const float*)d_in[7];
    const float* a_r          = (const float*)d_in[8];
    const float* a_e          = (const float*)d_in[9];
    const int* head_ind = edge_list;
    const int* tail_ind = edge_list + NE;

    // Workspace carve-up (~54 MB), 16B-aligned chunks first.
    // Xb (bf16 tail features, dead after proj) ALIASES exE+packed (born in
    // scatter) — region R sized max(25.6, 16) MB.
    char* ws = (char*)d_ws;
    unsigned short* h_tail = (unsigned short*)ws; ws += sizeof(unsigned short) * (size_t)N_TAILN * HD; // 25.6 MB
    unsigned short* Xb = (unsigned short*)ws;      // 25.6 MB region R
    float* exE    = (float*)(void*)Xb;                                          // alias: 12.8 MB
    int*   packed = (int*)(void*)((char*)(void*)Xb + sizeof(float) * (size_t)NE * HH); // alias: 3.2 MB
    ws += sizeof(unsigned short) * (size_t)N_TAILN * HD;
    short* Wt        = (short*)ws; ws += sizeof(short) * 256 * 256;              // 128 KB
    float* hl        = (float*)ws; ws += sizeof(float) * (size_t)N_HEADN * HH;   // 0.8 MB
    float* hr        = (float*)ws; ws += sizeof(float) * (size_t)N_TAILN * HH;   // 0.8 MB
    float* waT       = (float*)ws; ws += sizeof(float) * HH * 256;               // 4 KB
    float* he        = (float*)ws; ws += sizeof(float) * 32;                     // padded
    int*   counts    = (int*)ws;   ws += sizeof(int) * (size_t)N_HEADN;          // 0.2 MB
    int*   row_start = (int*)ws;   ws += sizeof(int) * (size_t)(N_HEADN + 4);    // 0.2 MB
    int*   cursor    = (int*)ws;   ws += sizeof(int) * (size_t)N_HEADN;          // 0.2 MB
    int*   blockSums = (int*)ws;   ws += sizeof(int) * 256;

    hipMemsetAsync(counts, 0, sizeof(int) * (size_t)N_HEADN, stream);

    // fused prep: hist | Xb cvt | waT | he | Wt — one dispatch
    hipLaunchKernelGGL(prep_kernel, dim3(NB_HIST + NB_CVT + 258), dim3(256), 0, stream,
                       head_ind, counts, tail_feature, Xb,
                       W, a_l, W_e, a_e, edge_emb, waT, he, Wt);

    hipLaunchKernelGGL(blocksum_kernel, dim3(NB_SCAN), dim3(256), 0, stream,
                       counts, blockSums);
    hipLaunchKernelGGL(rowstart_kernel, dim3(NB_SCAN), dim3(256), 0, stream,
                       counts, blockSums, row_start, cursor);

    hipLaunchKernelGGL(head_dot_kernel, dim3(N_HEADN / 4), dim3(256), 0, stream,
                       head_feature, waT, hl);
    hipLaunchKernelGGL(proj_mfma_kernel, dim3(NB_PROJ), dim3(256), 0, stream,
                       Xb, Wt, a_r, h_tail, hr);

    hipLaunchKernelGGL(scatter_kernel, dim3(NE / 256), dim3(256), 0, stream,
                       head_ind, tail_ind, tmp_edge, hl, hr, he, cursor, packed, exE);

    hipLaunchKernelGGL(agg_kernel, dim3(N_HEADN / 4), dim3(256), 0, stream,
                       row_start, packed, exE, h_tail, (float*)d_out);
}

// Round 7
// 332.246 us; speedup vs baseline: 1.1553x; 1.1409x over previous
//
#include <hip/hip_runtime.h>
#include <hip/hip_bf16.h>
#include <math.h>

// Problem constants (from reference)
#define N_HEADN 50000
#define N_TAILN 50000
#define NE      800000
#define F_IN    256
#define HH      4
#define HD      256   // H*D
#define FE      64
#define N_ETYPES 5
#define NEG_SLOPE 0.2f
#define NB_SCAN ((N_HEADN + 255) / 256)        // 196
#define NB_CVT  ((N_TAILN * F_IN) / (256 * 16)) // 3125
#define NB_HIST (NE / 256)                      // 3125
#define NT_PROJ (N_TAILN / 16)                  // 3125 row-tiles (exact)
#define NB_PROJ 256                             // 1 block per CU, grid-stride tiles

typedef __attribute__((ext_vector_type(8))) short bf16x8;
typedef __attribute__((ext_vector_type(4))) float f32x4;

// bf16 <-> fp32 (RNE), bit-level
static __device__ __forceinline__ unsigned short f2bf(float f) {
    unsigned u = __float_as_uint(f);
    return (unsigned short)((u + 0x7FFF + ((u >> 16) & 1)) >> 16);
}
static __device__ __forceinline__ float bf2f(unsigned short u) {
    return __uint_as_float((unsigned)u << 16);
}

// ---------------------------------------------------------------------------
// K_prep (fused):
//   blocks 0..NB_HIST-1                : histogram of head indices (counts
//                                        pre-zeroed by memsetAsync)
//   blocks NB_HIST..+NB_CVT-1          : Xb = bf16(X_tail) streaming cvt
//   block  NB_HIST+NB_CVT              : waT[h][k]
//   block  NB_HIST+NB_CVT+1            : he[ty][h]
//   blocks NB_HIST+NB_CVT+2 ..+257     : Wt[n][k] = bf16(W[k][n])
// ---------------------------------------------------------------------------
__global__ __launch_bounds__(256) void prep_kernel(const int* __restrict__ head,
                                                   int* __restrict__ counts,
                                                   const float* __restrict__ X,
                                                   unsigned short* __restrict__ Xb,
                                                   const float* __restrict__ W,
                                                   const float* __restrict__ a_l,
                                                   const float* __restrict__ W_e,
                                                   const float* __restrict__ a_e,
                                                   const float* __restrict__ edge_emb,
                                                   float* __restrict__ waT,
                                                   float* __restrict__ heo,
                                                   short* __restrict__ Wt) {
    const int b = blockIdx.x;
    if (b < NB_HIST) {
        int e = b * 256 + threadIdx.x;   // NE % 256 == 0
        atomicAdd(&counts[head[e]], 1);
    } else if (b < NB_HIST + NB_CVT) {
        size_t t = (size_t)(b - NB_HIST) * 256 + threadIdx.x;
        const float4* xp = (const float4*)X + t * 4;
        float4 v0 = xp[0], v1 = xp[1], v2 = xp[2], v3 = xp[3];
        bf16x8 o0, o1;
        o0[0] = (short)f2bf(v0.x); o0[1] = (short)f2bf(v0.y);
        o0[2] = (short)f2bf(v0.z); o0[3] = (short)f2bf(v0.w);
        o0[4] = (short)f2bf(v1.x); o0[5] = (short)f2bf(v1.y);
        o0[6] = (short)f2bf(v1.z); o0[7] = (short)f2bf(v1.w);
        o1[0] = (short)f2bf(v2.x); o1[1] = (short)f2bf(v2.y);
        o1[2] = (short)f2bf(v2.z); o1[3] = (short)f2bf(v2.w);
        o1[4] = (short)f2bf(v3.x); o1[5] = (short)f2bf(v3.y);
        o1[6] = (short)f2bf(v3.z); o1[7] = (short)f2bf(v3.w);
        bf16x8* op = (bf16x8*)(Xb + t * 16);
        op[0] = o0;
        op[1] = o1;
    } else if (b == NB_HIST + NB_CVT) {
        int k = threadIdx.x;   // 0..255
        #pragma unroll
        for (int h = 0; h < HH; ++h) {
            float s = 0.f;
            for (int d = 0; d < 64; ++d) s += a_l[h * 64 + d] * W[(size_t)k * HD + h * 64 + d];
            waT[h * 256 + k] = s;
        }
    } else if (b == NB_HIST + NB_CVT + 1) {
        __shared__ float wae[FE][HH];
        int t = threadIdx.x;          // 256 threads = 64 k x 4 h
        int k = t >> 2, h = t & 3;
        float s = 0.f;
        for (int f = 0; f < 64; ++f) s += a_e[h * 64 + f] * W_e[(size_t)k * (FE * HH) + h * 64 + f];
        wae[k][h] = s;
        __syncthreads();
        if (t < N_ETYPES * HH) {
            int ty = t >> 2, hh = t & 3;
            float acc = 0.f;
            for (int kk = 0; kk < FE; ++kk) acc += edge_emb[ty * FE + kk] * wae[kk][hh];
            heo[ty * HH + hh] = acc;
        }
    } else {
        int n = b - (NB_HIST + NB_CVT + 2), k = threadIdx.x;
        Wt[(size_t)n * 256 + k] = (short)f2bf(W[(size_t)k * 256 + n]);
    }
}

// ---------------------------------------------------------------------------
// K2a: per-block sums of counts
// ---------------------------------------------------------------------------
__global__ void blocksum_kernel(const int* __restrict__ counts, int* __restrict__ blockSums) {
    __shared__ int s[256];
    int t = threadIdx.x, j = blockIdx.x * 256 + t;
    s[t] = (j < N_HEADN) ? counts[j] : 0;
    __syncthreads();
    for (int off = 128; off > 0; off >>= 1) {
        if (t < off) s[t] += s[t + off];
        __syncthreads();
    }
    if (t == 0) blockSums[blockIdx.x] = s[0];
}

// ---------------------------------------------------------------------------
// K2b (fused): each block redundantly scans the 196 blockSums in LDS
// (inclusive; exclusive offset = bs[bid-1]), then scans its own 256 counts
// -> row_start, cursor.
// ---------------------------------------------------------------------------
__global__ void rowstart_kernel(const int* __restrict__ counts,
                                const int* __restrict__ blockSums,
                                int* __restrict__ row_start, int* __restrict__ cursor) {
    __shared__ int bs[256];
    __shared__ int s[256];
    int t = threadIdx.x, j = blockIdx.x * 256 + t;
    bs[t] = (t < NB_SCAN) ? blockSums[t] : 0;
    __syncthreads();
    for (int off = 1; off < 256; off <<= 1) {
        int u = (t >= off) ? bs[t - off] : 0;
        __syncthreads();
        bs[t] += u;
        __syncthreads();
    }
    const int blockOffV = (blockIdx.x == 0) ? 0 : bs[blockIdx.x - 1];
    int c = (j < N_HEADN) ? counts[j] : 0;
    s[t] = c;
    __syncthreads();
    for (int off = 1; off < 256; off <<= 1) {
        int u = (t >= off) ? s[t - off] : 0;
        __syncthreads();
        s[t] += u;
        __syncthreads();
    }
    int excl = blockOffV + s[t] - c;
    if (j < N_HEADN) {
        row_start[j] = excl;
        cursor[j]    = excl;
        if (j == N_HEADN - 1) row_start[N_HEADN] = excl + c;
    }
}

// ---------------------------------------------------------------------------
// K3a: hl = X_head @ waT^T  (thin GEMM, memory-bound). One wave per row.
// ---------------------------------------------------------------------------
__global__ __launch_bounds__(256) void head_dot_kernel(const float* __restrict__ X,
                                                       const float* __restrict__ waT,
                                                       float* __restrict__ hl) {
    const int wave = threadIdx.x >> 6;
    const int lane = threadIdx.x & 63;
    const int n = blockIdx.x * 4 + wave;   // N_HEADN % 4 == 0
    float4 x = ((const float4*)(X + (size_t)n * F_IN))[lane];
    float p[HH];
    #pragma unroll
    for (int h = 0; h < HH; ++h) {
        float4 w = ((const float4*)(waT + h * 256))[lane];
        p[h] = x.x * w.x + x.y * w.y + x.z * w.z + x.w * w.w;
    }
    #pragma unroll
    for (int off = 1; off < 64; off <<= 1) {
        #pragma unroll
        for (int h = 0; h < HH; ++h) p[h] += __shfl_xor(p[h], off);
    }
    if (lane < HH) hl[(size_t)n * HH + lane] = p[lane];
}

// ---------------------------------------------------------------------------
// K3b v4: h_tail = Xb(bf16) @ W, swapped-operand MFMA (D = Wt·Xb^T), with
// Wt staged ONCE per block in LDS (128 KB, 1 block/CU, grid=256).
// Round-6 diagnosis: 3 global-load proj variants all stuck at ~66us with
// ~3.3K serial cycles/wave == zero inter-wave latency hiding (L1 MSHR
// saturation on in-loop Wt loads). Fix: Wt from LDS (no MSHRs, 12cy
// throughput), Xb streamed with explicit ping-pong next-tile prefetch.
// LDS layout: col (w-col 0..255) x 32 chunks of 16B, chunk XOR-swizzled
// with (col&31) -> uniform 8-lanes/bank-group on ds_read_b128 (vs 4-way
// conflict unswizzled). Write side uses the same XOR (both-sides rule).
// A-frag from LDS Wt (m=w-col), B-frag xf (n=x-row); C/D col=lane&15 ->
// x-row, row=quad*4+reg -> w-col [m89-verified, round-6-passed].
// ---------------------------------------------------------------------------
struct ProjTileOut { };

static __device__ __forceinline__ void proj_load_xf(const unsigned short* __restrict__ Xb,
                                                    int tile, int l15, int quad,
                                                    bf16x8* xf) {
    const unsigned short* xbase = Xb + (size_t)(tile * 16 + l15) * F_IN + quad * 8;
    #pragma unroll
    for (int kk = 0; kk < 8; ++kk) xf[kk] = *(const bf16x8*)(xbase + kk * 32);
}

static __device__ __forceinline__ void proj_compute(const char* __restrict__ smem,
                                                    const float* __restrict__ a,
                                                    unsigned short* __restrict__ h_out,
                                                    float* __restrict__ hr,
                                                    int tile, int h, int lane,
                                                    const bf16x8* xf) {
    const int quad = lane >> 4;
    const int l15  = lane & 15;
    f32x4 acc[4];
    #pragma unroll
    for (int ct = 0; ct < 4; ++ct) acc[ct] = (f32x4){0.f, 0.f, 0.f, 0.f};

    // per-ct LDS base and swizzle key
    int colb[4], sw[4];
    #pragma unroll
    for (int ct = 0; ct < 4; ++ct) {
        int col = h * 64 + ct * 16 + l15;
        colb[ct] = col * 512;
        sw[ct]   = col & 31;
    }

    #pragma unroll
    for (int kk = 0; kk < 8; ++kk) {
        #pragma unroll
        for (int ct = 0; ct < 4; ++ct) {
            int addr = colb[ct] + ((((quad + kk * 4)) ^ sw[ct]) << 4);
            bf16x8 wf = *(const bf16x8*)(smem + addr);
            acc[ct] = __builtin_amdgcn_mfma_f32_16x16x32_bf16(wf, xf[kk], acc[ct], 0, 0, 0);
        }
    }

    const int row = tile * 16 + l15;
    float hp = 0.f;
    #pragma unroll
    for (int ct = 0; ct < 4; ++ct) {
        float4 av = *(const float4*)(a + h * 64 + ct * 16 + quad * 4);
        hp += av.x * acc[ct][0] + av.y * acc[ct][1]
            + av.z * acc[ct][2] + av.w * acc[ct][3];
        ushort4 pk;
        pk.x = f2bf(acc[ct][0]); pk.y = f2bf(acc[ct][1]);
        pk.z = f2bf(acc[ct][2]); pk.w = f2bf(acc[ct][3]);
        *(ushort4*)(h_out + (size_t)row * HD + h * 64 + ct * 16 + quad * 4) = pk;
    }
    hp += __shfl_xor(hp, 16);
    hp += __shfl_xor(hp, 32);
    if (lane < 16) hr[(size_t)row * HH + h] = hp;
}

__global__ __launch_bounds__(256) void proj_mfma_kernel(const unsigned short* __restrict__ Xb,
                                                        const short* __restrict__ Wt,
                                                        const float* __restrict__ a,
                                                        unsigned short* __restrict__ h_out,
                                                        float* __restrict__ hr) {
    extern __shared__ char smem[];       // 128 KB: 256 cols x 512 B, XOR-swizzled
    const int h    = threadIdx.x >> 6;   // wave = head 0..3
    const int lane = threadIdx.x & 63;
    const int l15  = lane & 15;
    const int quad = lane >> 4;

    // first tile prefetch (before staging, independent)
    int tile = blockIdx.x;
    bf16x8 xfA[8], xfB[8];
    if (tile < NT_PROJ) proj_load_xf(Xb, tile, l15, quad, xfA);

    // stage Wt -> LDS (cooperative, coalesced, swizzled write)
    {
        const int t = threadIdx.x;
        #pragma unroll
        for (int i = 0; i < 32; ++i) {
            int m = i * 256 + t;                 // 16B-chunk linear index
            bf16x8 v = *(const bf16x8*)(Wt + (size_t)m * 8);
            int col = m >> 5;
            int c   = m & 31;
            *(bf16x8*)(smem + col * 512 + ((c ^ (col & 31)) << 4)) = v;
        }
    }
    __syncthreads();

    // ping-pong over tiles: prefetch next while computing current
    while (tile < NT_PROJ) {
        int nxt = tile + NB_PROJ;
        if (nxt < NT_PROJ) proj_load_xf(Xb, nxt, l15, quad, xfB);
        proj_compute(smem, a, h_out, hr, tile, h, lane, xfA);
        tile = nxt;
        if (tile >= NT_PROJ) break;
        nxt = tile + NB_PROJ;
        if (nxt < NT_PROJ) proj_load_xf(Xb, nxt, l15, quad, xfA);
        proj_compute(smem, a, h_out, hr, tile, h, lane, xfB);
        tile = nxt;
    }
}

// ---------------------------------------------------------------------------
// K4: scatter each edge into its CSR slot; compute ex = exp(leaky(hl+hr+he))
// for all 4 heads here (edge-parallel). packed[pos] = tail; exE[pos][h] = ex.
// ---------------------------------------------------------------------------
__global__ void scatter_kernel(const int* __restrict__ head, const int* __restrict__ tail,
                               const int* __restrict__ etype,
                               const float* __restrict__ hl, const float* __restrict__ hr,
                               const float* __restrict__ he,
                               int* __restrict__ cursor, int* __restrict__ packed,
                               float* __restrict__ exE) {
    int e = blockIdx.x * 256 + threadIdx.x;   // NE % 256 == 0
    int h0 = head[e];
    int tl = tail[e];
    int ty = etype[e];
    float4 L = *(const float4*)(hl + (size_t)h0 * HH);
    float4 R = *(const float4*)(hr + (size_t)tl * HH);
    float4 T = *(const float4*)(he + ty * HH);
    float s0 = L.x + R.x + T.x;
    float s1 = L.y + R.y + T.y;
    float s2 = L.z + R.z + T.z;
    float s3 = L.w + R.w + T.w;
    s0 = (s0 > 0.f) ? s0 : NEG_SLOPE * s0;
    s1 = (s1 > 0.f) ? s1 : NEG_SLOPE * s1;
    s2 = (s2 > 0.f) ? s2 : NEG_SLOPE * s2;
    s3 = (s3 > 0.f) ? s3 : NEG_SLOPE * s3;
    float w0 = __expf(s0), w1 = __expf(s1), w2 = __expf(s2), w3 = __expf(s3);
    int pos = atomicAdd(&cursor[h0], 1);
    packed[pos] = tl;
    *(float4*)(exE + (size_t)pos * HH) = make_float4(w0, w1, w2, w3);
}

// ---------------------------------------------------------------------------
// K5: aggregation. One wave per head node. 2 edges/iteration, 32 lanes per
// edge, each lane one DENSE uint4 (16B) of the 512B h_tail row.
// ---------------------------------------------------------------------------
__global__ __launch_bounds__(256) void agg_kernel(const int* __restrict__ row_start,
                                                  const int* __restrict__ packed,
                                                  const float* __restrict__ exE,
                                                  const unsigned short* __restrict__ h_tail, // bf16
                                                  float* __restrict__ out) {
    const int wave = threadIdx.x >> 6;
    const int lane = threadIdx.x & 63;
    const int n = blockIdx.x * 4 + wave;      // N_HEADN % 4 == 0
    const int s = row_start[n];
    const int e = row_start[n + 1];
    const int g = lane >> 5;      // edge sub-stream 0..1
    const int q = lane & 31;      // column chunk: cols 8q..8q+7
    const int h = q >> 3;         // attention head for these cols

    float acc[8];
    #pragma unroll
    for (int c = 0; c < 8; ++c) acc[c] = 0.f;
    float z = 0.f;

    for (int base = s; base < e; base += 64) {
        const int cnt = (e - base < 64) ? (e - base) : 64;
        int myidx = 0;
        if (base + lane < e) myidx = packed[base + lane];
        #pragma unroll 8
        for (int i = 0; i < cnt; i += 2) {
            const int j = i + g;
            const int tl = __shfl(myidx, j);
            if (j < cnt) {
                const float w = exE[(size_t)(base + j) * HH + h];
                uint4 u = *(const uint4*)(h_tail + (size_t)tl * HD + q * 8);
                #pragma unroll
                for (int d = 0; d < 4; ++d) {
                    unsigned uu = ((const unsigned*)&u)[d];
                    acc[2 * d]     += w * __uint_as_float(uu << 16);
                    acc[2 * d + 1] += w * __uint_as_float(uu & 0xFFFF0000u);
                }
                z += w;
            }
        }
    }

    #pragma unroll
    for (int c = 0; c < 8; ++c) acc[c] += __shfl_xor(acc[c], 32);
    z += __shfl_xor(z, 32);

    float4 o;
    if (z > 0.f) {
        o.x = acc[4 * g + 0] / z;
        o.y = acc[4 * g + 1] / z;
        o.z = acc[4 * g + 2] / z;
        o.w = acc[4 * g + 3] / z;
        o.x = (o.x > 0.f) ? o.x : expm1f(o.x);
        o.y = (o.y > 0.f) ? o.y : expm1f(o.y);
        o.z = (o.z > 0.f) ? o.z : expm1f(o.z);
        o.w = (o.w > 0.f) ? o.w : expm1f(o.w);
    } else {
        o = make_float4(0.f, 0.f, 0.f, 0.f);
    }
    ((float4*)(out + (size_t)n * HD))[q * 2 + g] = o;
}

// ---------------------------------------------------------------------------
extern "C" void kernel_launch(void* const* d_in, const int* in_sizes, int n_in,
                              void* d_out, int out_size, void* d_ws, size_t ws_size,
                              hipStream_t stream) {
    const float* head_feature = (const float*)d_in[0];
    const float* tail_feature = (const float*)d_in[1];
    const int*   edge_list    = (const int*)d_in[2];   // [2, E]
    const int*   tmp_edge     = (const int*)d_in[3];   // [E]
    const float* W            = (const float*)d_in[4];
    const float* W_e          = (const float*)d_in[5];
    const float* edge_emb     = (const float*)d_in[6];
    const float* a_l          = (const float*)d_in[7];
    const float* a_r          = (const float*)d_in[8];
    const float* a_e          = (const float*)d_in[9];
    const int* head_ind = edge_list;
    const int* tail_ind = edge_list + NE;

    // Workspace carve-up (~54 MB), 16B-aligned chunks first.
    // Xb (bf16 tail features, dead after proj) ALIASES exE+packed.
    char* ws = (char*)d_ws;
    unsigned short* h_tail = (unsigned short*)ws; ws += sizeof(unsigned short) * (size_t)N_TAILN * HD; // 25.6 MB
    unsigned short* Xb = (unsigned short*)ws;      // 25.6 MB region R
    float* exE    = (float*)(void*)Xb;                                          // alias: 12.8 MB
    int*   packed = (int*)(void*)((char*)(void*)Xb + sizeof(float) * (size_t)NE * HH); // alias: 3.2 MB
    ws += sizeof(unsigned short) * (size_t)N_TAILN * HD;
    short* Wt        = (short*)ws; ws += sizeof(short) * 256 * 256;              // 128 KB
    float* hl        = (float*)ws; ws += sizeof(float) * (size_t)N_HEADN * HH;   // 0.8 MB
    float* hr        = (float*)ws; ws += sizeof(float) * (size_t)N_TAILN * HH;   // 0.8 MB
    float* waT       = (float*)ws; ws += sizeof(float) * HH * 256;               // 4 KB
    float* he        = (float*)ws; ws += sizeof(float) * 32;                     // padded
    int*   counts    = (int*)ws;   ws += sizeof(int) * (size_t)N_HEADN;          // 0.2 MB
    int*   row_start = (int*)ws;   ws += sizeof(int) * (size_t)(N_HEADN + 4);    // 0.2 MB
    int*   cursor    = (int*)ws;   ws += sizeof(int) * (size_t)N_HEADN;          // 0.2 MB
    int*   blockSums = (int*)ws;   ws += sizeof(int) * 256;

    hipMemsetAsync(counts, 0, sizeof(int) * (size_t)N_HEADN, stream);

    // fused prep: hist | Xb cvt | waT | he | Wt — one dispatch
    hipLaunchKernelGGL(prep_kernel, dim3(NB_HIST + NB_CVT + 258), dim3(256), 0, stream,
                       head_ind, counts, tail_feature, Xb,
                       W, a_l, W_e, a_e, edge_emb, waT, he, Wt);

    hipLaunchKernelGGL(blocksum_kernel, dim3(NB_SCAN), dim3(256), 0, stream,
                       counts, blockSums);
    hipLaunchKernelGGL(rowstart_kernel, dim3(NB_SCAN), dim3(256), 0, stream,
                       counts, blockSums, row_start, cursor);

    hipLaunchKernelGGL(head_dot_kernel, dim3(N_HEADN / 4), dim3(256), 0, stream,
                       head_feature, waT, hl);

    // proj: 1 block/CU, 128 KB dynamic LDS (allow >64KB defensively)
    static bool lds_attr_set = false;
    if (!lds_attr_set) {
        hipFuncSetAttribute((const void*)proj_mfma_kernel,
                            hipFuncAttributeMaxDynamicSharedMemorySize, 131072);
        lds_attr_set = true;
    }
    hipLaunchKernelGGL(proj_mfma_kernel, dim3(NB_PROJ), dim3(256), 131072, stream,
                       Xb, Wt, a_r, h_tail, hr);

    hipLaunchKernelGGL(scatter_kernel, dim3(NE / 256), dim3(256), 0, stream,
                       head_ind, tail_ind, tmp_edge, hl, hr, he, cursor, packed, exE);

    hipLaunchKernelGGL(agg_kernel, dim3(N_HEADN / 4), dim3(256), 0, stream,
                       row_start, packed, exE, h_tail, (float*)d_out);
}